// Round 10
// baseline (40.728 us; speedup 1.0000x reference)
//
#include <hip/hip_runtime.h>

#define EPS 1e-4f
#define INVN (1.0f/512.0f)

// Two kernels, both REGULAR launches:
//  K1 embed (1024 x 256, 4 blocks/CU = 16 waves/CU): block = 4 nodes; wave (p,h) =
//     node-pair p, d-half h (WAVE-level d-split: weight loads keep the one-128B-line
//     broadcast property that round-8's lane-level split broke). Partials combined
//     via LDS. Block 0 zeroes K2's barrier slots (sc0 sc1 -> LLC).
//  K2 sinkhorn (256 x 512): cost->K_sh (LDS) -> bar0 -> sv -> exp+u0+colparts -> bar1
//     -> v1 -> P = u0*K*v1. ONE Sinkhorn iteration (verified: absmax bit-identical
//     for ITERS=16/6/3/2/1). 2 spin-barriers (degree 32, per batch), relaxed agent
//     atomics, zero cache maintenance; cross-block data via sc0 sc1 (LLC).
//
// ws layout (bytes):
//   [0, 2048)         barrier one-shot slots (zeroed by K1 blk0): batch b at 256*b,
//                     cnt_i @ +4*i, flag_i @ +128+4*i
//   [4096, 5120)      partsum [8][32] f32
//   [8192, 532480)    aG [4096][32] f32  == alias ==  parts_A [8][32][512]
//                     (aG last read in K2 phase a, before bar0; parts_A written after bar0)
//   [532480, 1056768) bvG [4096][32] f32  (read only in K2 phase a)

__device__ __forceinline__ void store_f32_cg(float* p, float v) {
  asm volatile("global_store_dword %0, %1, off sc0 sc1" :: "v"(p), "v"(v) : "memory");
}

__device__ __forceinline__ float load_f32_cg(const float* p) {
  float r;
  asm volatile("global_load_dword %0, %1, off sc0 sc1\n\t"
               "s_waitcnt vmcnt(0)"
               : "=v"(r) : "v"(p) : "memory");
  return r;
}

// 8 float4 at 2048-byte row stride (k-slices of parts), one wait.
// p1 = slice kk=2 of this thread's group (offsets -4096..+2048 -> kk 0..3), p2 = kk 4..7.
__device__ __forceinline__ void load8x4_s2k_cg(const float* p1, const float* p2, float4* o) {
  asm volatile(
      "global_load_dwordx4 %0, %8, off offset:-4096 sc0 sc1\n\t"
      "global_load_dwordx4 %1, %8, off offset:-2048 sc0 sc1\n\t"
      "global_load_dwordx4 %2, %8, off sc0 sc1\n\t"
      "global_load_dwordx4 %3, %8, off offset:2048 sc0 sc1\n\t"
      "global_load_dwordx4 %4, %9, off offset:-4096 sc0 sc1\n\t"
      "global_load_dwordx4 %5, %9, off offset:-2048 sc0 sc1\n\t"
      "global_load_dwordx4 %6, %9, off sc0 sc1\n\t"
      "global_load_dwordx4 %7, %9, off offset:2048 sc0 sc1\n\t"
      "s_waitcnt vmcnt(0)"
      : "=&v"(o[0]), "=&v"(o[1]), "=&v"(o[2]), "=&v"(o[3]),
        "=&v"(o[4]), "=&v"(o[5]), "=&v"(o[6]), "=&v"(o[7])
      : "v"(p1), "v"(p2)
      : "memory");
}

__device__ __forceinline__ void batch_barrier(int* cnt, int* flag) {
  asm volatile("s_waitcnt vmcnt(0)" ::: "memory");   // drain write-through stores to LLC
  __syncthreads();
  if (threadIdx.x == 0) {
    int prev = __hip_atomic_fetch_add(cnt, 1, __ATOMIC_RELAXED, __HIP_MEMORY_SCOPE_AGENT);
    if (prev == 31) {
      __hip_atomic_store(flag, 1, __ATOMIC_RELAXED, __HIP_MEMORY_SCOPE_AGENT);
    } else {
      while (__hip_atomic_load(flag, __ATOMIC_RELAXED, __HIP_MEMORY_SCOPE_AGENT) == 0) {}
    }
  }
  __syncthreads();
}

// ---- Kernel 1: embed GEMVs. 1024 blocks x 256 threads.
// Block = 4 nodes. Wave w: p = w>>1 (node pair), h = w&1 (d-half, WAVE-uniform).
// Lane: r = lane>>5 (node in pair), m = lane&31. Weight loads: one 128B line/inst.
__global__ void __launch_bounds__(256)
embed_kernel(const float* __restrict__ emb_in, const void* __restrict__ maskp,
             const float* __restrict__ emb_out, const float* __restrict__ pad,
             const float* __restrict__ pos, const float* __restrict__ Win,
             const float* __restrict__ bin, const float* __restrict__ Wout,
             const float* __restrict__ bout,
             float* __restrict__ aG, float* __restrict__ bvG,
             char* __restrict__ ws) {
  const int t = threadIdx.x, blk = blockIdx.x;
  __shared__ unsigned dsh[2];
  __shared__ int mv_sh[4];
  __shared__ float psA[2][64], psB[2][64];

  if (blk == 0) {                      // zero barrier slots for K2 (write-through to LLC)
    store_f32_cg((float*)(ws + 4 * t), 0.0f);
    store_f32_cg((float*)(ws + 1024 + 4 * t), 0.0f);
  }

  if (t < 2) dsh[t] = 0u;
  __syncthreads();
  {
    // mask element-size detect on first 4096 bytes (dword-wise):
    // bool(1B): any byte i%4!=0 nonzero; int32: low byte of odd dwords nonzero; else int64.
    uint4 x = ((const uint4*)maskp)[t];
    unsigned orb = (x.x | x.y | x.z | x.w) & 0xFFFFFF00u;
    unsigned orc = (x.y | x.w) & 0xFFu;
    if (orb) atomicOr(&dsh[0], 1u);
    if (orc) atomicOr(&dsh[1], 1u);
  }
  __syncthreads();
  if (t < 4) {
    int g = blk * 4 + t;
    int mv;
    if (dsh[0])      mv = ((const unsigned char*)maskp)[g];
    else if (dsh[1]) mv = ((const int*)maskp)[g];
    else             mv = (int)(((const long long*)maskp)[g] != 0);
    mv_sh[t] = mv;
  }
  __syncthreads();

  const int w = t >> 6, lane = t & 63;
  const int p = w >> 1, h = w & 1;
  const int r = lane >> 5, m = lane & 31;
  const int g = blk * 4 + 2 * p + r, n = g & 511;
  const float* eo = emb_out + (size_t)g * 256 + h * 128;
  const float* po = pos + (size_t)n * 256 + h * 128;
  const float* ei = (mv_sh[2 * p + r] ? pad : (emb_in + (size_t)g * 256)) + h * 128;
  const float* Wo = Wout + (size_t)h * 128 * 32;
  const float* Wi = Win + (size_t)h * 128 * 32;
  float aa = 0.f, bb = 0.f;
  for (int d = 0; d < 128; d += 4) {
    float4 e4 = *(const float4*)(eo + d);
    float4 p4 = *(const float4*)(po + d);
    float4 i4 = *(const float4*)(ei + d);
    aa = fmaf(e4.x + p4.x, Wo[(d + 0) * 32 + m], aa);
    aa = fmaf(e4.y + p4.y, Wo[(d + 1) * 32 + m], aa);
    aa = fmaf(e4.z + p4.z, Wo[(d + 2) * 32 + m], aa);
    aa = fmaf(e4.w + p4.w, Wo[(d + 3) * 32 + m], aa);
    bb = fmaf(i4.x, Wi[(d + 0) * 32 + m], bb);
    bb = fmaf(i4.y, Wi[(d + 1) * 32 + m], bb);
    bb = fmaf(i4.z, Wi[(d + 2) * 32 + m], bb);
    bb = fmaf(i4.w, Wi[(d + 3) * 32 + m], bb);
  }
  if (h) { psA[p][lane] = aa; psB[p][lane] = bb; }
  __syncthreads();
  if (!h) {
    aa += psA[p][lane] + bout[m];
    bb += psB[p][lane] + bin[m];
    aG[(size_t)g * 32 + m] = aa;
    bvG[(size_t)g * 32 + m] = bb;
  }
}

// ---- Kernel 2: cost + 1-iter Sinkhorn + P. 256 blocks x 512 threads. ----
__global__ void __launch_bounds__(512)
sinkhorn_main(float* __restrict__ P, char* __restrict__ ws) {
  const int t = threadIdx.x;
  const int blk = blockIdx.x;
  const int b = blk & 7, loc = blk >> 3;     // batch <-> XCD affine (perf heuristic only)
  const int r0 = loc * 16;
  const int w = t >> 6, lane = t & 63;

  int* cnts  = (int*)(ws + 256 * b);
  int* flags = (int*)(ws + 256 * b + 128);
  float* partsumG = (float*)(ws + 4096);
  float* aG      = (float*)(ws + 8192);
  float* partsA  = (float*)(ws + 8192);
  float* bvG     = (float*)(ws + 532480);

  __shared__ float K_sh[16][512];        // 32 KB: C -> K, block-resident through P
  __shared__ float scratch_sh[8][512];   // 16 KB: colacc rows / v-reduce rows
  __shared__ float v_sh[512];
  __shared__ float a_sh[16][32];
  __shared__ float red_sh[8];
  __shared__ float sv_sh;

  // ---- Phase a: stage own a-rows (2 KB) + own bv column (plain cached loads;
  //      K1->K2 dispatch boundary provides coherence) ----
  float bva[32];
  {
    const float4* bj = (const float4*)(bvG + ((size_t)(b * 512) + t) * 32);
    float4 bq0 = bj[0], bq1 = bj[1], bq2 = bj[2], bq3 = bj[3];
    float4 bq4 = bj[4], bq5 = bj[5], bq6 = bj[6], bq7 = bj[7];
    ((float*)a_sh)[t] = aG[(size_t)(b * 512 + r0) * 32 + t];
    bva[0]=bq0.x; bva[1]=bq0.y; bva[2]=bq0.z; bva[3]=bq0.w;
    bva[4]=bq1.x; bva[5]=bq1.y; bva[6]=bq1.z; bva[7]=bq1.w;
    bva[8]=bq2.x; bva[9]=bq2.y; bva[10]=bq2.z; bva[11]=bq2.w;
    bva[12]=bq3.x; bva[13]=bq3.y; bva[14]=bq3.z; bva[15]=bq3.w;
    bva[16]=bq4.x; bva[17]=bq4.y; bva[18]=bq4.z; bva[19]=bq4.w;
    bva[20]=bq5.x; bva[21]=bq5.y; bva[22]=bq5.z; bva[23]=bq5.w;
    bva[24]=bq6.x; bva[25]=bq6.y; bva[26]=bq6.z; bva[27]=bq6.w;
    bva[28]=bq7.x; bva[29]=bq7.y; bva[30]=bq7.z; bva[31]=bq7.w;
  }
  __syncthreads();

  // ---- Phase b: C tile (16 rows x 512 cols), one column per thread, + partial sum ----
  {
    float csum = 0.f;
    for (int r = 0; r < 16; ++r) {
      const float4* ar4 = (const float4*)&a_sh[r][0];   // LDS broadcast reads
      float c0 = 0.f;
#pragma unroll
      for (int q = 0; q < 8; ++q) {
        float4 av = ar4[q];
        c0 += fabsf(av.x - bva[q * 4 + 0]) + fabsf(av.y - bva[q * 4 + 1])
            + fabsf(av.z - bva[q * 4 + 2]) + fabsf(av.w - bva[q * 4 + 3]);
      }
      K_sh[r][t] = c0;
      csum += c0;
    }
#pragma unroll
    for (int off = 1; off < 64; off <<= 1) csum += __shfl_xor(csum, off);
    if (lane == 0) red_sh[w] = csum;
    __syncthreads();
    if (t == 0) {
      float s = 0.f;
#pragma unroll
      for (int k = 0; k < 8; ++k) s += red_sh[k];
      store_f32_cg(partsumG + b * 32 + loc, s);
    }
  }
  batch_barrier(&cnts[0], &flags[0]);              // bar0: cost partials ready (aG dead)

  // ---- sv = -1/(EPS*S) ----
  if (t < 64) {
    float pv = (t < 32) ? load_f32_cg(partsumG + b * 32 + t) : 0.f;
#pragma unroll
    for (int off = 1; off < 64; off <<= 1) pv += __shfl_xor(pv, off);
    if (t == 0) sv_sh = -1.0f / (EPS * pv);
  }
  __syncthreads();
  const float sv = sv_sh;

  float u_last[2];
  const int w2 = t >> 7, idx = t & 127;
  float* partrowA = partsA + ((size_t)(b * 32) + loc) * 512;
  const float* vpA1 = partsA + (size_t)b * 32 * 512 + (size_t)(w2 * 8) * 512 + idx * 4 + 1024;
  const float* vpA2 = vpA1 + 2048;

  // ---- Phase c: K = exp(C*sv), u0 (v==1), column partials -> parts_A ----
  {
    float colacc[8] = {0, 0, 0, 0, 0, 0, 0, 0};
#pragma unroll
    for (int rr = 0; rr < 2; ++rr) {
      int r = 2 * w + rr;
      float4 c0 = *(float4*)&K_sh[r][4 * lane];
      float4 c1 = *(float4*)&K_sh[r][256 + 4 * lane];
      float kv[8];
      kv[0] = __expf(c0.x * sv); kv[1] = __expf(c0.y * sv);
      kv[2] = __expf(c0.z * sv); kv[3] = __expf(c0.w * sv);
      kv[4] = __expf(c1.x * sv); kv[5] = __expf(c1.y * sv);
      kv[6] = __expf(c1.z * sv); kv[7] = __expf(c1.w * sv);
      *(float4*)&K_sh[r][4 * lane]       = make_float4(kv[0], kv[1], kv[2], kv[3]);
      *(float4*)&K_sh[r][256 + 4 * lane] = make_float4(kv[4], kv[5], kv[6], kv[7]);
      float s = kv[0] + kv[1] + kv[2] + kv[3] + kv[4] + kv[5] + kv[6] + kv[7];
#pragma unroll
      for (int off = 1; off < 64; off <<= 1) s += __shfl_xor(s, off);
      float uu = INVN / s;
      u_last[rr] = uu;
#pragma unroll
      for (int q = 0; q < 8; ++q) colacc[q] = fmaf(kv[q], uu, colacc[q]);
    }
    *(float4*)&scratch_sh[w][4 * lane]       = make_float4(colacc[0], colacc[1], colacc[2], colacc[3]);
    *(float4*)&scratch_sh[w][256 + 4 * lane] = make_float4(colacc[4], colacc[5], colacc[6], colacc[7]);
    __syncthreads();
    float s0 = 0.f;
#pragma unroll
    for (int k = 0; k < 8; ++k) s0 += scratch_sh[k][t];
    store_f32_cg(partrowA + t, s0);
  }
  batch_barrier(&cnts[1], &flags[1]);              // bar1: parts_A ready

  // ---- Phase d: v1 from parts_A; P = u0 * K * v1 ----
  {
    float4 o[8];
    load8x4_s2k_cg(vpA1, vpA2, o);
    float4 acc = o[0];
    acc.x += o[1].x + o[2].x + o[3].x + o[4].x + o[5].x + o[6].x + o[7].x;
    acc.y += o[1].y + o[2].y + o[3].y + o[4].y + o[5].y + o[6].y + o[7].y;
    acc.z += o[1].z + o[2].z + o[3].z + o[4].z + o[5].z + o[6].z + o[7].z;
    acc.w += o[1].w + o[2].w + o[3].w + o[4].w + o[5].w + o[6].w + o[7].w;
    *(float4*)&scratch_sh[w2][4 * idx] = acc;
  }
  __syncthreads();
  v_sh[t] = INVN / (scratch_sh[0][t] + scratch_sh[1][t] + scratch_sh[2][t] + scratch_sh[3][t]);
  __syncthreads();
  {
    float4 v0 = *(float4*)&v_sh[4 * lane];
    float4 v1 = *(float4*)&v_sh[256 + 4 * lane];
#pragma unroll
    for (int rr = 0; rr < 2; ++rr) {
      int r = 2 * w + rr;
      float uu = u_last[rr];
      float4 k0 = *(float4*)&K_sh[r][4 * lane];
      float4 k1 = *(float4*)&K_sh[r][256 + 4 * lane];
      float4 o0 = make_float4(uu * k0.x * v0.x, uu * k0.y * v0.y,
                              uu * k0.z * v0.z, uu * k0.w * v0.w);
      float4 o1 = make_float4(uu * k1.x * v1.x, uu * k1.y * v1.y,
                              uu * k1.z * v1.z, uu * k1.w * v1.w);
      float* Prow = P + ((size_t)(b * 512) + r0 + r) * 512;
      *(float4*)(Prow + 4 * lane)       = o0;
      *(float4*)(Prow + 256 + 4 * lane) = o1;
    }
  }
}

extern "C" void kernel_launch(void* const* d_in, const int* in_sizes, int n_in,
                              void* d_out, int out_size, void* d_ws, size_t ws_size,
                              hipStream_t stream) {
  const float* emb_in  = (const float*)d_in[0];
  const void*  maskp   = d_in[1];
  const float* emb_out = (const float*)d_in[2];
  const float* pad     = (const float*)d_in[3];
  const float* pos     = (const float*)d_in[4];
  const float* Win     = (const float*)d_in[5];
  const float* bin     = (const float*)d_in[6];
  const float* Wout    = (const float*)d_in[7];
  const float* bout    = (const float*)d_in[8];
  float* P = (float*)d_out;
  char* ws = (char*)d_ws;
  float* aG  = (float*)(ws + 8192);
  float* bvG = (float*)(ws + 532480);

  embed_kernel<<<1024, 256, 0, stream>>>(emb_in, maskp, emb_out, pad, pos,
                                         Win, bin, Wout, bout, aG, bvG, ws);
  sinkhorn_main<<<256, 512, 0, stream>>>(P, ws);
}

// Round 11
// 35.499 us; speedup vs baseline: 1.1473x; 1.1473x over previous
//
#include <hip/hip_runtime.h>

#define EPS 1e-4f
#define INVN (1.0f/512.0f)

// Two kernels, both REGULAR launches:
//  K1 embed (512 x 256, LDS-staged weights): Win+Wout (64 KB) staged into LDS once per
//     block via coalesced float4 loads, then the GEMV inner loop reads weights from LDS
//     (conflict-free ds_read_b32, lanes = 32 consecutive words, node-pair broadcast).
//     Rationale: r9/r10 showed embed ~25us regardless of occupancy -> saturated L1 miss
//     path (weights 64KB > 32KB L1, thrashed by node streams, MSHR-bound). LDS removes
//     weight loads from L1 entirely; only 3 streaming float4 loads/iter remain.
//     Thread mapping identical to r7/r9 (grid 512, 8 nodes/block, r=t>>5, m=t&31) ->
//     bit-identical arithmetic. Block 0 zeroes K2's barrier slots (sc0 sc1 -> LLC).
//  K2 sinkhorn (256 x 512, UNCHANGED from r9/r10): cost->K_sh (LDS) -> bar0 -> sv ->
//     exp+u0+colparts -> bar1 -> v1 -> P = u0*K*v1. ONE Sinkhorn iteration (verified:
//     absmax bit-identical for ITERS=16/6/3/2/1). 2 spin-barriers (degree 32, per
//     batch), relaxed agent atomics, zero cache maintenance; cross-block data via
//     sc0 sc1 (LLC write-through / LLC loads).
//
// ws layout (bytes):
//   [0, 2048)         barrier one-shot slots (zeroed by K1 blk0): batch b at 256*b,
//                     cnt_i @ +4*i, flag_i @ +128+4*i
//   [4096, 5120)      partsum [8][32] f32
//   [8192, 532480)    aG [4096][32] f32  == alias ==  parts_A [8][32][512]
//                     (aG last read in K2 phase a, before bar0; parts_A written after bar0)
//   [532480, 1056768) bvG [4096][32] f32  (read only in K2 phase a)

__device__ __forceinline__ void store_f32_cg(float* p, float v) {
  asm volatile("global_store_dword %0, %1, off sc0 sc1" :: "v"(p), "v"(v) : "memory");
}

__device__ __forceinline__ float load_f32_cg(const float* p) {
  float r;
  asm volatile("global_load_dword %0, %1, off sc0 sc1\n\t"
               "s_waitcnt vmcnt(0)"
               : "=v"(r) : "v"(p) : "memory");
  return r;
}

// 8 float4 at 2048-byte row stride (k-slices of parts), one wait.
// p1 = slice kk=2 of this thread's group (offsets -4096..+2048 -> kk 0..3), p2 = kk 4..7.
__device__ __forceinline__ void load8x4_s2k_cg(const float* p1, const float* p2, float4* o) {
  asm volatile(
      "global_load_dwordx4 %0, %8, off offset:-4096 sc0 sc1\n\t"
      "global_load_dwordx4 %1, %8, off offset:-2048 sc0 sc1\n\t"
      "global_load_dwordx4 %2, %8, off sc0 sc1\n\t"
      "global_load_dwordx4 %3, %8, off offset:2048 sc0 sc1\n\t"
      "global_load_dwordx4 %4, %9, off offset:-4096 sc0 sc1\n\t"
      "global_load_dwordx4 %5, %9, off offset:-2048 sc0 sc1\n\t"
      "global_load_dwordx4 %6, %9, off sc0 sc1\n\t"
      "global_load_dwordx4 %7, %9, off offset:2048 sc0 sc1\n\t"
      "s_waitcnt vmcnt(0)"
      : "=&v"(o[0]), "=&v"(o[1]), "=&v"(o[2]), "=&v"(o[3]),
        "=&v"(o[4]), "=&v"(o[5]), "=&v"(o[6]), "=&v"(o[7])
      : "v"(p1), "v"(p2)
      : "memory");
}

__device__ __forceinline__ void batch_barrier(int* cnt, int* flag) {
  asm volatile("s_waitcnt vmcnt(0)" ::: "memory");   // drain write-through stores to LLC
  __syncthreads();
  if (threadIdx.x == 0) {
    int prev = __hip_atomic_fetch_add(cnt, 1, __ATOMIC_RELAXED, __HIP_MEMORY_SCOPE_AGENT);
    if (prev == 31) {
      __hip_atomic_store(flag, 1, __ATOMIC_RELAXED, __HIP_MEMORY_SCOPE_AGENT);
    } else {
      while (__hip_atomic_load(flag, __ATOMIC_RELAXED, __HIP_MEMORY_SCOPE_AGENT) == 0) {}
    }
  }
  __syncthreads();
}

// ---- Kernel 1: embed GEMVs. 512 blocks x 256 threads, block = 8 nodes x 32 m.
// Weights LDS-staged (64 KB); inner-loop weight reads are conflict-free ds_read_b32.
__global__ void __launch_bounds__(256)
embed_kernel(const float* __restrict__ emb_in, const void* __restrict__ maskp,
             const float* __restrict__ emb_out, const float* __restrict__ pad,
             const float* __restrict__ pos, const float* __restrict__ Win,
             const float* __restrict__ bin, const float* __restrict__ Wout,
             const float* __restrict__ bout,
             float* __restrict__ aG, float* __restrict__ bvG,
             char* __restrict__ ws) {
  const int t = threadIdx.x, blk = blockIdx.x;
  __shared__ float Wo_lds[8192];       // Wout [256][32], 32 KB
  __shared__ float Wi_lds[8192];       // Win  [256][32], 32 KB
  __shared__ unsigned dsh[2];
  __shared__ int mv_sh[8];

  if (blk == 0 && t < 256) {           // zero barrier slots for K2 (write-through to LLC)
    store_f32_cg((float*)(ws + 4 * t), 0.0f);
    store_f32_cg((float*)(ws + 1024 + 4 * t), 0.0f);
  }

  // stage weights: 8 coalesced float4 per matrix per thread
#pragma unroll
  for (int k = 0; k < 8; ++k) {
    int i4 = k * 256 + t;              // f4 index 0..2047
    ((float4*)Wo_lds)[i4] = ((const float4*)Wout)[i4];
    ((float4*)Wi_lds)[i4] = ((const float4*)Win)[i4];
  }

  if (t < 2) dsh[t] = 0u;
  __syncthreads();
  {
    // mask element-size detect on first 4096 bytes (dword-wise):
    // bool(1B): any byte i%4!=0 nonzero; int32: low byte of odd dwords nonzero; else int64.
    uint4 x = ((const uint4*)maskp)[t];
    unsigned orb = (x.x | x.y | x.z | x.w) & 0xFFFFFF00u;
    unsigned orc = (x.y | x.w) & 0xFFu;
    if (orb) atomicOr(&dsh[0], 1u);
    if (orc) atomicOr(&dsh[1], 1u);
  }
  __syncthreads();
  if (t < 8) {
    int g = blk * 8 + t;
    int mv;
    if (dsh[0])      mv = ((const unsigned char*)maskp)[g];
    else if (dsh[1]) mv = ((const int*)maskp)[g];
    else             mv = (int)(((const long long*)maskp)[g] != 0);
    mv_sh[t] = mv;
  }
  __syncthreads();

  const int r = t >> 5, m = t & 31;
  const int g = blk * 8 + r, n = g & 511;
  const float* eo = emb_out + (size_t)g * 256;
  const float* po = pos + (size_t)n * 256;
  const float* ei = mv_sh[r] ? pad : (emb_in + (size_t)g * 256);
  float aa = bout[m], bb = bin[m];
  for (int d = 0; d < 256; d += 4) {
    float4 e4 = *(const float4*)(eo + d);
    float4 p4 = *(const float4*)(po + d);
    float4 i4 = *(const float4*)(ei + d);
    aa = fmaf(e4.x + p4.x, Wo_lds[(d + 0) * 32 + m], aa);
    aa = fmaf(e4.y + p4.y, Wo_lds[(d + 1) * 32 + m], aa);
    aa = fmaf(e4.z + p4.z, Wo_lds[(d + 2) * 32 + m], aa);
    aa = fmaf(e4.w + p4.w, Wo_lds[(d + 3) * 32 + m], aa);
    bb = fmaf(i4.x, Wi_lds[(d + 0) * 32 + m], bb);
    bb = fmaf(i4.y, Wi_lds[(d + 1) * 32 + m], bb);
    bb = fmaf(i4.z, Wi_lds[(d + 2) * 32 + m], bb);
    bb = fmaf(i4.w, Wi_lds[(d + 3) * 32 + m], bb);
  }
  aG[(size_t)g * 32 + m] = aa;
  bvG[(size_t)g * 32 + m] = bb;
}

// ---- Kernel 2: cost + 1-iter Sinkhorn + P. 256 blocks x 512 threads. (unchanged) ----
__global__ void __launch_bounds__(512)
sinkhorn_main(float* __restrict__ P, char* __restrict__ ws) {
  const int t = threadIdx.x;
  const int blk = blockIdx.x;
  const int b = blk & 7, loc = blk >> 3;     // batch <-> XCD affine (perf heuristic only)
  const int r0 = loc * 16;
  const int w = t >> 6, lane = t & 63;

  int* cnts  = (int*)(ws + 256 * b);
  int* flags = (int*)(ws + 256 * b + 128);
  float* partsumG = (float*)(ws + 4096);
  float* aG      = (float*)(ws + 8192);
  float* partsA  = (float*)(ws + 8192);
  float* bvG     = (float*)(ws + 532480);

  __shared__ float K_sh[16][512];        // 32 KB: C -> K, block-resident through P
  __shared__ float scratch_sh[8][512];   // 16 KB: colacc rows / v-reduce rows
  __shared__ float v_sh[512];
  __shared__ float a_sh[16][32];
  __shared__ float red_sh[8];
  __shared__ float sv_sh;

  // ---- Phase a: stage own a-rows (2 KB) + own bv column (plain cached loads;
  //      K1->K2 dispatch boundary provides coherence) ----
  float bva[32];
  {
    const float4* bj = (const float4*)(bvG + ((size_t)(b * 512) + t) * 32);
    float4 bq0 = bj[0], bq1 = bj[1], bq2 = bj[2], bq3 = bj[3];
    float4 bq4 = bj[4], bq5 = bj[5], bq6 = bj[6], bq7 = bj[7];
    ((float*)a_sh)[t] = aG[(size_t)(b * 512 + r0) * 32 + t];
    bva[0]=bq0.x; bva[1]=bq0.y; bva[2]=bq0.z; bva[3]=bq0.w;
    bva[4]=bq1.x; bva[5]=bq1.y; bva[6]=bq1.z; bva[7]=bq1.w;
    bva[8]=bq2.x; bva[9]=bq2.y; bva[10]=bq2.z; bva[11]=bq2.w;
    bva[12]=bq3.x; bva[13]=bq3.y; bva[14]=bq3.z; bva[15]=bq3.w;
    bva[16]=bq4.x; bva[17]=bq4.y; bva[18]=bq4.z; bva[19]=bq4.w;
    bva[20]=bq5.x; bva[21]=bq5.y; bva[22]=bq5.z; bva[23]=bq5.w;
    bva[24]=bq6.x; bva[25]=bq6.y; bva[26]=bq6.z; bva[27]=bq6.w;
    bva[28]=bq7.x; bva[29]=bq7.y; bva[30]=bq7.z; bva[31]=bq7.w;
  }
  __syncthreads();

  // ---- Phase b: C tile (16 rows x 512 cols), one column per thread, + partial sum ----
  {
    float csum = 0.f;
    for (int r = 0; r < 16; ++r) {
      const float4* ar4 = (const float4*)&a_sh[r][0];   // LDS broadcast reads
      float c0 = 0.f;
#pragma unroll
      for (int q = 0; q < 8; ++q) {
        float4 av = ar4[q];
        c0 += fabsf(av.x - bva[q * 4 + 0]) + fabsf(av.y - bva[q * 4 + 1])
            + fabsf(av.z - bva[q * 4 + 2]) + fabsf(av.w - bva[q * 4 + 3]);
      }
      K_sh[r][t] = c0;
      csum += c0;
    }
#pragma unroll
    for (int off = 1; off < 64; off <<= 1) csum += __shfl_xor(csum, off);
    if (lane == 0) red_sh[w] = csum;
    __syncthreads();
    if (t == 0) {
      float s = 0.f;
#pragma unroll
      for (int k = 0; k < 8; ++k) s += red_sh[k];
      store_f32_cg(partsumG + b * 32 + loc, s);
    }
  }
  batch_barrier(&cnts[0], &flags[0]);              // bar0: cost partials ready (aG dead)

  // ---- sv = -1/(EPS*S) ----
  if (t < 64) {
    float pv = (t < 32) ? load_f32_cg(partsumG + b * 32 + t) : 0.f;
#pragma unroll
    for (int off = 1; off < 64; off <<= 1) pv += __shfl_xor(pv, off);
    if (t == 0) sv_sh = -1.0f / (EPS * pv);
  }
  __syncthreads();
  const float sv = sv_sh;

  float u_last[2];
  const int w2 = t >> 7, idx = t & 127;
  float* partrowA = partsA + ((size_t)(b * 32) + loc) * 512;
  const float* vpA1 = partsA + (size_t)b * 32 * 512 + (size_t)(w2 * 8) * 512 + idx * 4 + 1024;
  const float* vpA2 = vpA1 + 2048;

  // ---- Phase c: K = exp(C*sv), u0 (v==1), column partials -> parts_A ----
  {
    float colacc[8] = {0, 0, 0, 0, 0, 0, 0, 0};
#pragma unroll
    for (int rr = 0; rr < 2; ++rr) {
      int r = 2 * w + rr;
      float4 c0 = *(float4*)&K_sh[r][4 * lane];
      float4 c1 = *(float4*)&K_sh[r][256 + 4 * lane];
      float kv[8];
      kv[0] = __expf(c0.x * sv); kv[1] = __expf(c0.y * sv);
      kv[2] = __expf(c0.z * sv); kv[3] = __expf(c0.w * sv);
      kv[4] = __expf(c1.x * sv); kv[5] = __expf(c1.y * sv);
      kv[6] = __expf(c1.z * sv); kv[7] = __expf(c1.w * sv);
      *(float4*)&K_sh[r][4 * lane]       = make_float4(kv[0], kv[1], kv[2], kv[3]);
      *(float4*)&K_sh[r][256 + 4 * lane] = make_float4(kv[4], kv[5], kv[6], kv[7]);
      float s = kv[0] + kv[1] + kv[2] + kv[3] + kv[4] + kv[5] + kv[6] + kv[7];
#pragma unroll
      for (int off = 1; off < 64; off <<= 1) s += __shfl_xor(s, off);
      float uu = INVN / s;
      u_last[rr] = uu;
#pragma unroll
      for (int q = 0; q < 8; ++q) colacc[q] = fmaf(kv[q], uu, colacc[q]);
    }
    *(float4*)&scratch_sh[w][4 * lane]       = make_float4(colacc[0], colacc[1], colacc[2], colacc[3]);
    *(float4*)&scratch_sh[w][256 + 4 * lane] = make_float4(colacc[4], colacc[5], colacc[6], colacc[7]);
    __syncthreads();
    float s0 = 0.f;
#pragma unroll
    for (int k = 0; k < 8; ++k) s0 += scratch_sh[k][t];
    store_f32_cg(partrowA + t, s0);
  }
  batch_barrier(&cnts[1], &flags[1]);              // bar1: parts_A ready

  // ---- Phase d: v1 from parts_A; P = u0 * K * v1 ----
  {
    float4 o[8];
    load8x4_s2k_cg(vpA1, vpA2, o);
    float4 acc = o[0];
    acc.x += o[1].x + o[2].x + o[3].x + o[4].x + o[5].x + o[6].x + o[7].x;
    acc.y += o[1].y + o[2].y + o[3].y + o[4].y + o[5].y + o[6].y + o[7].y;
    acc.z += o[1].z + o[2].z + o[3].z + o[4].z + o[5].z + o[6].z + o[7].z;
    acc.w += o[1].w + o[2].w + o[3].w + o[4].w + o[5].w + o[6].w + o[7].w;
    *(float4*)&scratch_sh[w2][4 * idx] = acc;
  }
  __syncthreads();
  v_sh[t] = INVN / (scratch_sh[0][t] + scratch_sh[1][t] + scratch_sh[2][t] + scratch_sh[3][t]);
  __syncthreads();
  {
    float4 v0 = *(float4*)&v_sh[4 * lane];
    float4 v1 = *(float4*)&v_sh[256 + 4 * lane];
#pragma unroll
    for (int rr = 0; rr < 2; ++rr) {
      int r = 2 * w + rr;
      float uu = u_last[rr];
      float4 k0 = *(float4*)&K_sh[r][4 * lane];
      float4 k1 = *(float4*)&K_sh[r][256 + 4 * lane];
      float4 o0 = make_float4(uu * k0.x * v0.x, uu * k0.y * v0.y,
                              uu * k0.z * v0.z, uu * k0.w * v0.w);
      float4 o1 = make_float4(uu * k1.x * v1.x, uu * k1.y * v1.y,
                              uu * k1.z * v1.z, uu * k1.w * v1.w);
      float* Prow = P + ((size_t)(b * 512) + r0 + r) * 512;
      *(float4*)(Prow + 4 * lane)       = o0;
      *(float4*)(Prow + 256 + 4 * lane) = o1;
    }
  }
}

extern "C" void kernel_launch(void* const* d_in, const int* in_sizes, int n_in,
                              void* d_out, int out_size, void* d_ws, size_t ws_size,
                              hipStream_t stream) {
  const float* emb_in  = (const float*)d_in[0];
  const void*  maskp   = d_in[1];
  const float* emb_out = (const float*)d_in[2];
  const float* pad     = (const float*)d_in[3];
  const float* pos     = (const float*)d_in[4];
  const float* Win     = (const float*)d_in[5];
  const float* bin     = (const float*)d_in[6];
  const float* Wout    = (const float*)d_in[7];
  const float* bout    = (const float*)d_in[8];
  float* P = (float*)d_out;
  char* ws = (char*)d_ws;
  float* aG  = (float*)(ws + 8192);
  float* bvG = (float*)(ws + 532480);

  embed_kernel<<<512, 256, 0, stream>>>(emb_in, maskp, emb_out, pad, pos,
                                        Win, bin, Wout, bout, aG, bvG, ws);
  sinkhorn_main<<<256, 512, 0, stream>>>(P, ws);
}

// Round 12
// 30.514 us; speedup vs baseline: 1.3347x; 1.1634x over previous
//
#include <hip/hip_runtime.h>

#define EPS 1e-4f
#define INVN (1.0f/512.0f)

// Two kernels, both REGULAR launches:
//  K1 embed (256 x 512, FULLY LDS-STAGED): node streams (emb_out/pos/emb_in|pad, 48 KB)
//     staged with COALESCED float4 loads (1 KB fresh bytes per wave-inst), weights
//     (64 KB) staged as in r11. Inner GEMV loop reads only LDS. Rationale: r9-r11 showed
//     K1 ~20us regardless of occupancy/weight-staging -> the broadcast node loads
//     (all 32 lanes same address = 32 fresh B/wave-inst) were latency-throttling at
//     ~0.5 TB/s effective. Coalesced staging restores full HBM BW. FMA order identical
//     to r11 -> bit-identical aG/bvG. Block 0 zeroes K2's barrier slots.
//  K2 sinkhorn (256 x 512, UNCHANGED r9-r11): cost->K_sh (LDS) -> bar0 -> sv ->
//     exp+u0+colparts -> bar1 -> v1 -> P = u0*K*v1. ONE Sinkhorn iteration (verified:
//     absmax bit-identical for ITERS=16/6/3/2/1). 2 spin-barriers (degree 32, per
//     batch), relaxed agent atomics, zero cache maintenance; cross-block data via
//     sc0 sc1 (LLC write-through / LLC loads).
//
// ws layout (bytes):
//   [0, 2048)         barrier one-shot slots (zeroed by K1 blk0): batch b at 256*b,
//                     cnt_i @ +4*i, flag_i @ +128+4*i
//   [4096, 5120)      partsum [8][32] f32
//   [8192, 532480)    aG [4096][32] f32  == alias ==  parts_A [8][32][512]
//                     (aG last read in K2 phase a, before bar0; parts_A written after bar0)
//   [532480, 1056768) bvG [4096][32] f32  (read only in K2 phase a)

__device__ __forceinline__ void store_f32_cg(float* p, float v) {
  asm volatile("global_store_dword %0, %1, off sc0 sc1" :: "v"(p), "v"(v) : "memory");
}

__device__ __forceinline__ float load_f32_cg(const float* p) {
  float r;
  asm volatile("global_load_dword %0, %1, off sc0 sc1\n\t"
               "s_waitcnt vmcnt(0)"
               : "=v"(r) : "v"(p) : "memory");
  return r;
}

// 8 float4 at 2048-byte row stride (k-slices of parts), one wait.
// p1 = slice kk=2 of this thread's group (offsets -4096..+2048 -> kk 0..3), p2 = kk 4..7.
__device__ __forceinline__ void load8x4_s2k_cg(const float* p1, const float* p2, float4* o) {
  asm volatile(
      "global_load_dwordx4 %0, %8, off offset:-4096 sc0 sc1\n\t"
      "global_load_dwordx4 %1, %8, off offset:-2048 sc0 sc1\n\t"
      "global_load_dwordx4 %2, %8, off sc0 sc1\n\t"
      "global_load_dwordx4 %3, %8, off offset:2048 sc0 sc1\n\t"
      "global_load_dwordx4 %4, %9, off offset:-4096 sc0 sc1\n\t"
      "global_load_dwordx4 %5, %9, off offset:-2048 sc0 sc1\n\t"
      "global_load_dwordx4 %6, %9, off sc0 sc1\n\t"
      "global_load_dwordx4 %7, %9, off offset:2048 sc0 sc1\n\t"
      "s_waitcnt vmcnt(0)"
      : "=&v"(o[0]), "=&v"(o[1]), "=&v"(o[2]), "=&v"(o[3]),
        "=&v"(o[4]), "=&v"(o[5]), "=&v"(o[6]), "=&v"(o[7])
      : "v"(p1), "v"(p2)
      : "memory");
}

__device__ __forceinline__ void batch_barrier(int* cnt, int* flag) {
  asm volatile("s_waitcnt vmcnt(0)" ::: "memory");   // drain write-through stores to LLC
  __syncthreads();
  if (threadIdx.x == 0) {
    int prev = __hip_atomic_fetch_add(cnt, 1, __ATOMIC_RELAXED, __HIP_MEMORY_SCOPE_AGENT);
    if (prev == 31) {
      __hip_atomic_store(flag, 1, __ATOMIC_RELAXED, __HIP_MEMORY_SCOPE_AGENT);
    } else {
      while (__hip_atomic_load(flag, __ATOMIC_RELAXED, __HIP_MEMORY_SCOPE_AGENT) == 0) {}
    }
  }
  __syncthreads();
}

// ---- Kernel 1: embed GEMVs. 256 blocks x 512 threads, block = 16 nodes x 32 m.
// Everything LDS-staged; all global reads coalesced.
__global__ void __launch_bounds__(512)
embed_kernel(const float* __restrict__ emb_in, const void* __restrict__ maskp,
             const float* __restrict__ emb_out, const float* __restrict__ pad,
             const float* __restrict__ pos, const float* __restrict__ Win,
             const float* __restrict__ bin, const float* __restrict__ Wout,
             const float* __restrict__ bout,
             float* __restrict__ aG, float* __restrict__ bvG,
             char* __restrict__ ws) {
  const int t = threadIdx.x, blk = blockIdx.x;
  __shared__ float Wo_lds[8192];       // Wout [256][32], 32 KB
  __shared__ float Wi_lds[8192];       // Win  [256][32], 32 KB
  __shared__ float eo_lds[4096];       // emb_out rows, 16 KB
  __shared__ float po_lds[4096];       // pos rows, 16 KB
  __shared__ float ei_lds[4096];       // emb_in|pad rows, 16 KB
  __shared__ unsigned dsh[2];
  __shared__ int mv_sh[16];

  if (blk == 0) {                      // zero barrier slots for K2 (write-through to LLC)
    store_f32_cg((float*)(ws + 4 * t), 0.0f);   // t<512 covers [0,2048)
  }

  // stage weights: 4 coalesced float4 per matrix per thread
#pragma unroll
  for (int k = 0; k < 4; ++k) {
    int i4 = k * 512 + t;              // f4 index 0..2047
    ((float4*)Wo_lds)[i4] = ((const float4*)Wout)[i4];
    ((float4*)Wi_lds)[i4] = ((const float4*)Win)[i4];
  }
  // stage emb_out + pos rows (contiguous 16 KB each), coalesced
  {
    const float4* eo4 = (const float4*)(emb_out + (size_t)blk * 16 * 256);
    const float4* po4 = (const float4*)(pos + (size_t)((blk * 16) & 511) * 256);
    ((float4*)eo_lds)[t]       = eo4[t];
    ((float4*)eo_lds)[t + 512] = eo4[t + 512];
    ((float4*)po_lds)[t]       = po4[t];
    ((float4*)po_lds)[t + 512] = po4[t + 512];
  }

  if (t < 2) dsh[t] = 0u;
  __syncthreads();
  if (t < 256) {
    // mask element-size detect on first 4096 bytes (dword-wise):
    // bool(1B): any byte i%4!=0 nonzero; int32: low byte of odd dwords nonzero; else int64.
    uint4 x = ((const uint4*)maskp)[t];
    unsigned orb = (x.x | x.y | x.z | x.w) & 0xFFFFFF00u;
    unsigned orc = (x.y | x.w) & 0xFFu;
    if (orb) atomicOr(&dsh[0], 1u);
    if (orc) atomicOr(&dsh[1], 1u);
  }
  __syncthreads();
  if (t < 16) {
    int g = blk * 16 + t;
    int mv;
    if (dsh[0])      mv = ((const unsigned char*)maskp)[g];
    else if (dsh[1]) mv = ((const int*)maskp)[g];
    else             mv = (int)(((const long long*)maskp)[g] != 0);
    mv_sh[t] = mv;
  }
  __syncthreads();
  // stage emb_in|pad rows (mask select per node), coalesced
  {
    const float4* ein4 = (const float4*)(emb_in + (size_t)blk * 16 * 256);
    const float4* pad4 = (const float4*)pad;
#pragma unroll
    for (int k = 0; k < 2; ++k) {
      int i4 = k * 512 + t;            // 0..1023; node = i4>>6, j = i4&63
      ((float4*)ei_lds)[i4] = mv_sh[i4 >> 6] ? pad4[i4 & 63] : ein4[i4];
    }
  }
  __syncthreads();

  const int r = t >> 5, m = t & 31;
  const int g = blk * 16 + r;
  const float* eo = eo_lds + r * 256;
  const float* po = po_lds + r * 256;
  const float* ei = ei_lds + r * 256;
  float aa = bout[m], bb = bin[m];
  for (int d = 0; d < 256; d += 4) {
    float4 e4 = *(const float4*)(eo + d);   // LDS broadcast (32 lanes same addr)
    float4 p4 = *(const float4*)(po + d);
    float4 i4 = *(const float4*)(ei + d);
    aa = fmaf(e4.x + p4.x, Wo_lds[(d + 0) * 32 + m], aa);
    aa = fmaf(e4.y + p4.y, Wo_lds[(d + 1) * 32 + m], aa);
    aa = fmaf(e4.z + p4.z, Wo_lds[(d + 2) * 32 + m], aa);
    aa = fmaf(e4.w + p4.w, Wo_lds[(d + 3) * 32 + m], aa);
    bb = fmaf(i4.x, Wi_lds[(d + 0) * 32 + m], bb);
    bb = fmaf(i4.y, Wi_lds[(d + 1) * 32 + m], bb);
    bb = fmaf(i4.z, Wi_lds[(d + 2) * 32 + m], bb);
    bb = fmaf(i4.w, Wi_lds[(d + 3) * 32 + m], bb);
  }
  aG[(size_t)g * 32 + m] = aa;
  bvG[(size_t)g * 32 + m] = bb;
}

// ---- Kernel 2: cost + 1-iter Sinkhorn + P. 256 blocks x 512 threads. (unchanged) ----
__global__ void __launch_bounds__(512)
sinkhorn_main(float* __restrict__ P, char* __restrict__ ws) {
  const int t = threadIdx.x;
  const int blk = blockIdx.x;
  const int b = blk & 7, loc = blk >> 3;     // batch <-> XCD affine (perf heuristic only)
  const int r0 = loc * 16;
  const int w = t >> 6, lane = t & 63;

  int* cnts  = (int*)(ws + 256 * b);
  int* flags = (int*)(ws + 256 * b + 128);
  float* partsumG = (float*)(ws + 4096);
  float* aG      = (float*)(ws + 8192);
  float* partsA  = (float*)(ws + 8192);
  float* bvG     = (float*)(ws + 532480);

  __shared__ float K_sh[16][512];        // 32 KB: C -> K, block-resident through P
  __shared__ float scratch_sh[8][512];   // 16 KB: colacc rows / v-reduce rows
  __shared__ float v_sh[512];
  __shared__ float a_sh[16][32];
  __shared__ float red_sh[8];
  __shared__ float sv_sh;

  // ---- Phase a: stage own a-rows (2 KB) + own bv column (plain cached loads;
  //      K1->K2 dispatch boundary provides coherence) ----
  float bva[32];
  {
    const float4* bj = (const float4*)(bvG + ((size_t)(b * 512) + t) * 32);
    float4 bq0 = bj[0], bq1 = bj[1], bq2 = bj[2], bq3 = bj[3];
    float4 bq4 = bj[4], bq5 = bj[5], bq6 = bj[6], bq7 = bj[7];
    ((float*)a_sh)[t] = aG[(size_t)(b * 512 + r0) * 32 + t];
    bva[0]=bq0.x; bva[1]=bq0.y; bva[2]=bq0.z; bva[3]=bq0.w;
    bva[4]=bq1.x; bva[5]=bq1.y; bva[6]=bq1.z; bva[7]=bq1.w;
    bva[8]=bq2.x; bva[9]=bq2.y; bva[10]=bq2.z; bva[11]=bq2.w;
    bva[12]=bq3.x; bva[13]=bq3.y; bva[14]=bq3.z; bva[15]=bq3.w;
    bva[16]=bq4.x; bva[17]=bq4.y; bva[18]=bq4.z; bva[19]=bq4.w;
    bva[20]=bq5.x; bva[21]=bq5.y; bva[22]=bq5.z; bva[23]=bq5.w;
    bva[24]=bq6.x; bva[25]=bq6.y; bva[26]=bq6.z; bva[27]=bq6.w;
    bva[28]=bq7.x; bva[29]=bq7.y; bva[30]=bq7.z; bva[31]=bq7.w;
  }
  __syncthreads();

  // ---- Phase b: C tile (16 rows x 512 cols), one column per thread, + partial sum ----
  {
    float csum = 0.f;
    for (int r = 0; r < 16; ++r) {
      const float4* ar4 = (const float4*)&a_sh[r][0];   // LDS broadcast reads
      float c0 = 0.f;
#pragma unroll
      for (int q = 0; q < 8; ++q) {
        float4 av = ar4[q];
        c0 += fabsf(av.x - bva[q * 4 + 0]) + fabsf(av.y - bva[q * 4 + 1])
            + fabsf(av.z - bva[q * 4 + 2]) + fabsf(av.w - bva[q * 4 + 3]);
      }
      K_sh[r][t] = c0;
      csum += c0;
    }
#pragma unroll
    for (int off = 1; off < 64; off <<= 1) csum += __shfl_xor(csum, off);
    if (lane == 0) red_sh[w] = csum;
    __syncthreads();
    if (t == 0) {
      float s = 0.f;
#pragma unroll
      for (int k = 0; k < 8; ++k) s += red_sh[k];
      store_f32_cg(partsumG + b * 32 + loc, s);
    }
  }
  batch_barrier(&cnts[0], &flags[0]);              // bar0: cost partials ready (aG dead)

  // ---- sv = -1/(EPS*S) ----
  if (t < 64) {
    float pv = (t < 32) ? load_f32_cg(partsumG + b * 32 + t) : 0.f;
#pragma unroll
    for (int off = 1; off < 64; off <<= 1) pv += __shfl_xor(pv, off);
    if (t == 0) sv_sh = -1.0f / (EPS * pv);
  }
  __syncthreads();
  const float sv = sv_sh;

  float u_last[2];
  const int w2 = t >> 7, idx = t & 127;
  float* partrowA = partsA + ((size_t)(b * 32) + loc) * 512;
  const float* vpA1 = partsA + (size_t)b * 32 * 512 + (size_t)(w2 * 8) * 512 + idx * 4 + 1024;
  const float* vpA2 = vpA1 + 2048;

  // ---- Phase c: K = exp(C*sv), u0 (v==1), column partials -> parts_A ----
  {
    float colacc[8] = {0, 0, 0, 0, 0, 0, 0, 0};
#pragma unroll
    for (int rr = 0; rr < 2; ++rr) {
      int r = 2 * w + rr;
      float4 c0 = *(float4*)&K_sh[r][4 * lane];
      float4 c1 = *(float4*)&K_sh[r][256 + 4 * lane];
      float kv[8];
      kv[0] = __expf(c0.x * sv); kv[1] = __expf(c0.y * sv);
      kv[2] = __expf(c0.z * sv); kv[3] = __expf(c0.w * sv);
      kv[4] = __expf(c1.x * sv); kv[5] = __expf(c1.y * sv);
      kv[6] = __expf(c1.z * sv); kv[7] = __expf(c1.w * sv);
      *(float4*)&K_sh[r][4 * lane]       = make_float4(kv[0], kv[1], kv[2], kv[3]);
      *(float4*)&K_sh[r][256 + 4 * lane] = make_float4(kv[4], kv[5], kv[6], kv[7]);
      float s = kv[0] + kv[1] + kv[2] + kv[3] + kv[4] + kv[5] + kv[6] + kv[7];
#pragma unroll
      for (int off = 1; off < 64; off <<= 1) s += __shfl_xor(s, off);
      float uu = INVN / s;
      u_last[rr] = uu;
#pragma unroll
      for (int q = 0; q < 8; ++q) colacc[q] = fmaf(kv[q], uu, colacc[q]);
    }
    *(float4*)&scratch_sh[w][4 * lane]       = make_float4(colacc[0], colacc[1], colacc[2], colacc[3]);
    *(float4*)&scratch_sh[w][256 + 4 * lane] = make_float4(colacc[4], colacc[5], colacc[6], colacc[7]);
    __syncthreads();
    float s0 = 0.f;
#pragma unroll
    for (int k = 0; k < 8; ++k) s0 += scratch_sh[k][t];
    store_f32_cg(partrowA + t, s0);
  }
  batch_barrier(&cnts[1], &flags[1]);              // bar1: parts_A ready

  // ---- Phase d: v1 from parts_A; P = u0 * K * v1 ----
  {
    float4 o[8];
    load8x4_s2k_cg(vpA1, vpA2, o);
    float4 acc = o[0];
    acc.x += o[1].x + o[2].x + o[3].x + o[4].x + o[5].x + o[6].x + o[7].x;
    acc.y += o[1].y + o[2].y + o[3].y + o[4].y + o[5].y + o[6].y + o[7].y;
    acc.z += o[1].z + o[2].z + o[3].z + o[4].z + o[5].z + o[6].z + o[7].z;
    acc.w += o[1].w + o[2].w + o[3].w + o[4].w + o[5].w + o[6].w + o[7].w;
    *(float4*)&scratch_sh[w2][4 * idx] = acc;
  }
  __syncthreads();
  v_sh[t] = INVN / (scratch_sh[0][t] + scratch_sh[1][t] + scratch_sh[2][t] + scratch_sh[3][t]);
  __syncthreads();
  {
    float4 v0 = *(float4*)&v_sh[4 * lane];
    float4 v1 = *(float4*)&v_sh[256 + 4 * lane];
#pragma unroll
    for (int rr = 0; rr < 2; ++rr) {
      int r = 2 * w + rr;
      float uu = u_last[rr];
      float4 k0 = *(float4*)&K_sh[r][4 * lane];
      float4 k1 = *(float4*)&K_sh[r][256 + 4 * lane];
      float4 o0 = make_float4(uu * k0.x * v0.x, uu * k0.y * v0.y,
                              uu * k0.z * v0.z, uu * k0.w * v0.w);
      float4 o1 = make_float4(uu * k1.x * v1.x, uu * k1.y * v1.y,
                              uu * k1.z * v1.z, uu * k1.w * v1.w);
      float* Prow = P + ((size_t)(b * 512) + r0 + r) * 512;
      *(float4*)(Prow + 4 * lane)       = o0;
      *(float4*)(Prow + 256 + 4 * lane) = o1;
    }
  }
}

extern "C" void kernel_launch(void* const* d_in, const int* in_sizes, int n_in,
                              void* d_out, int out_size, void* d_ws, size_t ws_size,
                              hipStream_t stream) {
  const float* emb_in  = (const float*)d_in[0];
  const void*  maskp   = d_in[1];
  const float* emb_out = (const float*)d_in[2];
  const float* pad     = (const float*)d_in[3];
  const float* pos     = (const float*)d_in[4];
  const float* Win     = (const float*)d_in[5];
  const float* bin     = (const float*)d_in[6];
  const float* Wout    = (const float*)d_in[7];
  const float* bout    = (const float*)d_in[8];
  float* P = (float*)d_out;
  char* ws = (char*)d_ws;
  float* aG  = (float*)(ws + 8192);
  float* bvG = (float*)(ws + 532480);

  embed_kernel<<<256, 512, 0, stream>>>(emb_in, maskp, emb_out, pad, pos,
                                        Win, bin, Wout, bout, aG, bvG, ws);
  sinkhorn_main<<<256, 512, 0, stream>>>(P, ws);
}